// Round 9
// baseline (1134.239 us; speedup 1.0000x reference)
//
#include <hip/hip_runtime.h>

// ConvLSTM B=8,T=16,CIN=16,HID=64,H=W=64,K=3 'SAME' — PERSISTENT kernel.
// Round-12: drop ALL hand-rolled sc0/sc1 asm coherence (2 NaN rounds: the
// invented protocol, not the flag logic, was the suspect). Cross-block h
// exchange now uses the COMPILER's memory model only:
//   producer: plain stores -> __syncthreads (drains to L2) -> tid0
//             __threadfence (wbl2: flush dirty L2 to IC) -> release fdone.
//   consumer: tid0 relaxed-spin fdone -> __threadfence (inv L1/L2) ->
//             barrier -> plain staging loads (fetch fresh from IC).
// Design: 256 blocks (1/CU, all resident), +-1 y-band neighbor DAG flags
// (fdone = h published, fstag = inputs consumed; monotone counters ->
// deadlock-free), c in VGPRs all 16 steps (cbuf deleted), one-time LDS
// zero/bias, K-loop = round-9 fully-unrolled tap-major 2-ahead.

#define B_ 8
#define T_ 16
#define CIN_ 16
#define HID_ 64
#define H_ 64
#define W_ 64
#define HW_ (H_*W_)
#define CTOT_ 80
#define XS_ROW 66                  // 64 px + 2 halo
#define XS_CH 104                  // 96 K-channels + 8 pad
#define XS_SIZE (4*XS_ROW*XS_CH)   // 27456 hw = 54912 B
#define CSTRIDE_ (B_*HID_*HW_)     // 2097152

typedef __attribute__((ext_vector_type(8))) short short8;
typedef __attribute__((ext_vector_type(4))) float f32x4;

__device__ __forceinline__ unsigned short f2bf(float f){
    unsigned u = __float_as_uint(f);
    u = (u + 0x7FFFu + ((u >> 16) & 1u)) >> 16;   // RNE
    return (unsigned short)u;
}
__device__ __forceinline__ float sigm_(float v){ return 1.0f/(1.0f + __expf(-v)); }
__device__ __forceinline__ float tanh_(float v){ return 2.0f/(1.0f + __expf(-2.0f*v)) - 1.0f; }

__device__ __forceinline__ void wait_ge(int* f, int v){
    while (__hip_atomic_load(f, __ATOMIC_RELAXED, __HIP_MEMORY_SCOPE_AGENT) < v)
        __builtin_amdgcn_s_sleep(2);
}
__device__ __forceinline__ void st_flag(int* f, int v){
    __hip_atomic_store(f, v, __ATOMIC_RELEASE, __HIP_MEMORY_SCOPE_AGENT);
}

// Wfrag: [tap 9][cc 3][ng 16] frags of 512 hw ([lane][j]).
// n = ng*16+(lane&15): g=n>>6, o=n&63; k-ch c = cc*32+(lane>>4)*8+j.
// Bias folded at c==80 (constant-1 A channel), center tap only.
__global__ void prep_wfrag(const float* __restrict__ Wf, const float* __restrict__ Wi,
                           const float* __restrict__ Wc, const float* __restrict__ Wo,
                           const float* __restrict__ bf, const float* __restrict__ bi,
                           const float* __restrict__ bc, const float* __restrict__ bo,
                           unsigned short* __restrict__ Wfrag, int* __restrict__ flags){
    if (blockIdx.x == 0){                            // reset BOTH flag arrays
        flags[threadIdx.x]       = 0;                // fdone[256]
        flags[256 + threadIdx.x] = 0;                // fstag[256]
    }
    int idx = blockIdx.x*256 + threadIdx.x;          // 864*256 = 221184 exact
    int j    = idx & 7;
    int lane = (idx >> 3) & 63;
    int frag = idx >> 9;
    int ng = frag & 15;
    int tc = frag >> 4;
    int cc = tc % 3, tap = tc / 3;
    int n = ng*16 + (lane & 15);
    int g = n >> 6, o = n & 63;
    int c = cc*32 + ((lane >> 4) << 3) + j;
    int ky = tap / 3, kx = tap % 3;
    float v = 0.0f;
    if (c < CTOT_){
        if (g == 0)      v = Wf[((o*CTOT_ + c)*3 + ky)*3 + kx];
        else if (g == 1) v = Wi[((o*CTOT_ + c)*3 + ky)*3 + kx];
        else if (g == 2) v = Wc[((o*CTOT_ + c)*3 + ky)*3 + kx];
        else             v = (tap == 4) ? Wo[o*CTOT_ + c] : 0.0f;
    } else if (c == CTOT_ && tap == 4){              // bias channel
        v = (g==0) ? bf[o] : (g==1) ? bi[o] : (g==2) ? bc[o] : bo[o];
    }
    Wfrag[idx] = f2bf(v);
}

// x[b][t][c][y][px] fp32 -> xbf[b][t][y][px][c16] bf16 (vector-stageable)
__global__ void prep_xbf(const float* __restrict__ x, unsigned short* __restrict__ xbf){
    int idx = blockIdx.x*256 + threadIdx.x;          // 524288 = (b,t,y,px) flat
    int px = idx & 63;
    int y  = (idx >> 6) & 63;
    int bt = idx >> 12;
    const float* src = x + (size_t)bt*CIN_*HW_ + y*W_ + px;
    unsigned short tmp[16];
    #pragma unroll
    for (int c = 0; c < 16; ++c) tmp[c] = f2bf(src[(size_t)c*HW_]);
    uint4* dst = (uint4*)(xbf + (size_t)idx*16);
    dst[0] = *(uint4*)(tmp);
    dst[1] = *(uint4*)(tmp + 8);
}

__global__ __launch_bounds__(512, 1) void lstm_persist(
    const unsigned short* __restrict__ xbf,
    const unsigned short* __restrict__ Wfrag,
    unsigned short* __restrict__ hbA,                // h ring buffer 0
    unsigned short* __restrict__ hbB,                // h ring buffer 1
    float* __restrict__ out,                         // [h|c] std layout, t==15
    int* __restrict__ flags)                         // done[256] | staged[256]
{
    __shared__ __align__(16) unsigned short Xs[XS_SIZE];
    int* fdone = flags;
    int* fstag = flags + 256;

    const int id   = blockIdx.x;
    // XCD swizzle: id&7 -> XCD; each XCD owns a contiguous 8-row y band so
    // y+-1 halo reads stay XCD-local. 256 blocks = 32/XCD = 1/CU.
    const int xcd  = id & 7;
    const int j    = id >> 3;
    const int b    = j >> 2;
    const int y0   = xcd*8 + ((j & 3) << 1);         // row-pair start
    const int yp   = xcd*4 + (j & 3);                // y-pair index 0..31
    // neighbor block ids (same b, yp+-1); id' = ((b*4 + (yp'&3))<<3) | (yp'>>2)
    const int bu   = (yp > 0)  ? (((b*4 + ((yp-1)&3)) << 3) | ((yp-1) >> 2)) : -1;
    const int bd   = (yp < 31) ? (((b*4 + ((yp+1)&3)) << 3) | ((yp+1) >> 2)) : -1;
    const int tid  = threadIdx.x;
    const int lane = tid & 63;
    const int wid  = tid >> 6;
    const int wm   = wid >> 2;                       // 0/1: which output row
    const int wn   = wid & 3;                        // N-slice
    const int l15  = lane & 15;
    const int q    = lane >> 4;

    // ---- one-time LDS init: zero all (covers OOB rows, halo cols, pad ch,
    // and the h region for t==0); bias 1.0 set after the t=0 top barrier.
    uint4 z4; z4.x=z4.y=z4.z=z4.w=0u;
    for (int i = tid; i < XS_SIZE/8; i += 512) ((uint4*)Xs)[i] = z4;

    // ---- c state lives in registers across all 16 steps
    float cr[4][4];
    #pragma unroll
    for (int mf = 0; mf < 4; ++mf)
        #pragma unroll
        for (int r = 0; r < 4; ++r) cr[mf][r] = 0.0f;

    const unsigned short* Abase = Xs + (size_t)(wm*XS_ROW + l15)*XS_CH + q*8;
    const unsigned short* Bbase = Wfrag + (size_t)wn*512 + lane*8;
    const int o = wn*16 + l15;
    const int y = y0 + wm;

    #pragma unroll 1
    for (int t = 0; t < T_; ++t){
        const unsigned short* hi = (t & 1) ? hbA : hbB;
        unsigned short*       ho = (t & 1) ? hbB : hbA;

        // ---- wait: neighbors published h(t-1); then acquire-fence (inv L1/L2)
        if (t > 0 && tid == 0){
            if (bu >= 0) wait_ge(fdone + bu, t);
            if (bd >= 0) wait_ge(fdone + bd, t);
            __threadfence();                          // inv: see fresh h from IC
        }
        __syncthreads();   // also fences prev K-loop Xs reads vs staging below

        if (t == 0){       // bias channel 1.0 (persists; OOB rows feed 0 wts)
            for (int i = tid; i < 4*XS_ROW; i += 512)
                Xs[i*XS_CH + CTOT_] = 0x3F80;
        }
        // ---- stage h: 4 rows x 64 px x 8 ch8 = 2048 uint4 (4/thread), plain
        uint4 hv[4]; bool hok[4] = {false,false,false,false};
        int hrow[4], hpx[4], hch8[4];
        if (t > 0){
            #pragma unroll
            for (int k = 0; k < 4; ++k){
                int i = tid + (k << 9);
                hrow[k] = i >> 9; int rem = i & 511; hpx[k] = rem >> 3; hch8[k] = rem & 7;
                int yy = y0 + hrow[k] - 1;
                if (yy >= 0 && yy < H_){
                    hok[k] = true;
                    hv[k] = *(const uint4*)(hi + ((((size_t)b*H_ + yy)*W_ + hpx[k])*HID_ + hch8[k]*8));
                }
            }
        }
        // ---- stage x: 4 rows x 64 px x 2 ch8 = 512 uint4 (1/thread)
        {
            int row = tid >> 7, rem = tid & 127;
            int px = rem >> 1, ch8 = rem & 1;
            int yy = y0 + row - 1;
            if (yy >= 0 && yy < H_){
                uint4 v = *(const uint4*)(xbf + ((((size_t)(b*T_ + t)*H_ + yy)*W_ + px)*16 + ch8*8));
                *(uint4*)(Xs + ((size_t)(row*XS_ROW + px + 1))*XS_CH + ch8*8) = v;
            }
        }
        if (t > 0){
            #pragma unroll
            for (int k = 0; k < 4; ++k)
                if (hok[k])
                    *(uint4*)(Xs + (size_t)(hrow[k]*XS_ROW + hpx[k] + 1)*XS_CH + CIN_ + hch8[k]*8) = hv[k];
        }
        __syncthreads();   // pre-barrier waitcnt drains all staging loads
        if (t > 0 && tid == 0) st_flag(fstag + id, t + 1);  // inputs of t consumed

        // ---- K-loop: 27 tc iters, fully unrolled, tap-major, 2-ahead prefetch
        f32x4 acc[4][4];
        #pragma unroll
        for (int g = 0; g < 4; ++g){
            #pragma unroll
            for (int mf = 0; mf < 4; ++mf) acc[g][mf] = (f32x4)0.0f;
        }
        short8 a[3][4], bb[3][3], bO[3];
        #pragma unroll
        for (int p = 0; p < 2; ++p){                 // preload tc=0,1
            const int tap = p/3, cc = p%3;
            const int ky = tap/3, kx = tap%3;
            const int aoff = (ky*XS_ROW + kx)*XS_CH + cc*32;
            #pragma unroll
            for (int mf = 0; mf < 4; ++mf)
                a[p][mf] = *(const short8*)(Abase + aoff + mf*16*XS_CH);
            #pragma unroll
            for (int g = 0; g < 3; ++g)
                bb[p][g] = *(const short8*)(Bbase + p*8192 + g*2048);
        }
        #pragma unroll
        for (int tc = 0; tc < 27; ++tc){
            const int tap = tc/3;
            const int cur = tc % 3;
            if (tc + 2 < 27){
                const int ntc = tc + 2;
                const int nxt = ntc % 3;
                const int ntap = ntc/3, ncc = ntc%3;
                const int nky = ntap/3, nkx = ntap%3;
                const int aoff = (nky*XS_ROW + nkx)*XS_CH + ncc*32;
                #pragma unroll
                for (int mf = 0; mf < 4; ++mf)
                    a[nxt][mf] = *(const short8*)(Abase + aoff + mf*16*XS_CH);
                #pragma unroll
                for (int g = 0; g < 3; ++g)
                    bb[nxt][g] = *(const short8*)(Bbase + ntc*8192 + g*2048);
            }
            if (tc >= 10 && tc <= 12)                // o-gate frags for tc=12,13,14
                bO[tc-10] = *(const short8*)(Bbase + (tc+2)*8192 + 6144);
            if (tap == 4){
                #pragma unroll
                for (int mf = 0; mf < 4; ++mf)
                    acc[3][mf] = __builtin_amdgcn_mfma_f32_16x16x32_bf16(a[cur][mf], bO[tc-12], acc[3][mf], 0,0,0);
            }
            #pragma unroll
            for (int g = 0; g < 3; ++g){
                #pragma unroll
                for (int mf = 0; mf < 4; ++mf)
                    acc[g][mf] = __builtin_amdgcn_mfma_f32_16x16x32_bf16(a[cur][mf], bb[cur][g], acc[g][mf], 0,0,0);
            }
        }

        // ---- throttle: writing ho (buffer t&1, holds my t-2 output) requires
        // neighbors to have finished staging step t-1 (they read that buffer).
        if (t >= 2 && tid == 0){
            if (bu >= 0) wait_ge(fstag + bu, t);
            if (bd >= 0) wait_ge(fstag + bd, t);
        }
        __syncthreads();

        // ---- epilogue: gates; c in registers; h via plain stores
        #pragma unroll
        for (int mf = 0; mf < 4; ++mf){
            #pragma unroll
            for (int r = 0; r < 4; ++r){
                const int px = mf*16 + q*4 + r;
                const float fv = sigm_(acc[0][mf][r]);
                const float iv = sigm_(acc[1][mf][r]);
                const float gv = tanh_(acc[2][mf][r]);
                const float ov = sigm_(acc[3][mf][r]);
                const float cn = cr[mf][r]*fv + iv*gv;
                const float hn = tanh_(cn)*ov;
                cr[mf][r] = cn;
                if (t < T_-1){
                    ho[(((size_t)(b*H_ + y)*W_ + px)*HID_ + o)] = f2bf(hn);
                } else {
                    const size_t oidx = ((((size_t)(b*HID_ + o))*H_ + y)*W_ + px);
                    out[oidx] = hn;
                    out[CSTRIDE_ + oidx] = cn;
                }
            }
        }
        // publish: barrier (drains all waves' stores into L2) -> tid0 flushes
        // L2 to the coherent point (wbl2) -> release fdone.
        __syncthreads();
        if (t < T_-1 && tid == 0){
            __threadfence();
            st_flag(fdone + id, t + 1);
        }
    }
}

extern "C" void kernel_launch(void* const* d_in, const int* in_sizes, int n_in,
                              void* d_out, int out_size, void* d_ws, size_t ws_size,
                              hipStream_t stream){
    const float* x  = (const float*)d_in[0];
    const float* Wf = (const float*)d_in[1];
    const float* bf = (const float*)d_in[2];
    const float* Wi = (const float*)d_in[3];
    const float* bi = (const float*)d_in[4];
    const float* Wc = (const float*)d_in[5];
    const float* bc = (const float*)d_in[6];
    const float* Wo = (const float*)d_in[7];
    const float* bo = (const float*)d_in[8];

    // ws: Wfrag 442368 | xbf 16777216 | hbA 4194304 | hbB 4194304 | flags 2048
    unsigned short* Wfrag = (unsigned short*)d_ws;
    unsigned short* xbf   = (unsigned short*)((char*)d_ws + 442368);
    unsigned short* hbA   = (unsigned short*)((char*)d_ws + 17219584);
    unsigned short* hbB   = (unsigned short*)((char*)d_ws + 21413888);
    int*            flags = (int*)((char*)d_ws + 25608192);

    prep_wfrag<<<dim3(864), dim3(256), 0, stream>>>(Wf, Wi, Wc, Wo, bf, bi, bc, bo, Wfrag, flags);
    prep_xbf<<<dim3(2048), dim3(256), 0, stream>>>(x, xbf);
    lstm_persist<<<dim3(256), dim3(512), 0, stream>>>(xbf, Wfrag, hbA, hbB, (float*)d_out, flags);
}

// Round 10
// 390.650 us; speedup vs baseline: 2.9035x; 2.9035x over previous
//
#include <hip/hip_runtime.h>

// ConvLSTM B=8,T=16,CIN=16,HID=64,H=W=64,K=3 'SAME' — 16-launch bf16 MFMA.
// Round-13: REVERT persistent experiment (round-12 PMC: __threadfence =
// agent fence = per-step L2 wb+inv -> Wfrag refetched 324KB x 256blk x 16t
// = 1.33GB, FETCH 2MB->1.17GB, 2.9x slower. The 16-launch path keeps L2
// warm across launches — launches ARE the cheap grid barrier. Lesson filed.)
// Base = round-9 (397us best: 256blk x 512thr, M=128, fully-unrolled
// tap-major K-loop). Two bounded deltas:
//  (1) B-prefetch depth 2 -> 3 (bb[4][3]; o-gate frags at distance 3):
//      covers ~240cy of B L2 latency vs ~160cy wave-time at 2 waves/SIMD.
//  (2) targeted LDS init (proven correct in passing round-7): pad/halo/OOB
//      regions only (~350 uint4 vs 3432) and drops one __syncthreads.

#define B_ 8
#define T_ 16
#define CIN_ 16
#define HID_ 64
#define H_ 64
#define W_ 64
#define HW_ (H_*W_)
#define CTOT_ 80
#define XS_ROW 66                  // 64 px + 2 halo
#define XS_CH 104                  // 96 K-channels + 8 pad
#define XS_SIZE (4*XS_ROW*XS_CH)   // 27456 hw = 54912 B
#define CSTRIDE_ (B_*HID_*HW_)     // 2097152

typedef __attribute__((ext_vector_type(8))) short short8;
typedef __attribute__((ext_vector_type(4))) float f32x4;

__device__ __forceinline__ unsigned short f2bf(float f){
    unsigned u = __float_as_uint(f);
    u = (u + 0x7FFFu + ((u >> 16) & 1u)) >> 16;   // RNE
    return (unsigned short)u;
}
__device__ __forceinline__ float sigm_(float v){ return 1.0f/(1.0f + __expf(-v)); }
__device__ __forceinline__ float tanh_(float v){ return 2.0f/(1.0f + __expf(-2.0f*v)) - 1.0f; }

// Wfrag: [tap 9][cc 3][ng 16] frags of 512 hw ([lane][j]).
// n = ng*16+(lane&15): g=n>>6, o=n&63; k-ch c = cc*32+(lane>>4)*8+j.
// Bias folded at c==80 (constant-1 A channel), center tap only.
__global__ void prep_wfrag(const float* __restrict__ Wf, const float* __restrict__ Wi,
                           const float* __restrict__ Wc, const float* __restrict__ Wo,
                           const float* __restrict__ bf, const float* __restrict__ bi,
                           const float* __restrict__ bc, const float* __restrict__ bo,
                           unsigned short* __restrict__ Wfrag){
    int idx = blockIdx.x*256 + threadIdx.x;          // 864*256 = 221184 exact
    int j    = idx & 7;
    int lane = (idx >> 3) & 63;
    int frag = idx >> 9;
    int ng = frag & 15;
    int tc = frag >> 4;
    int cc = tc % 3, tap = tc / 3;
    int n = ng*16 + (lane & 15);
    int g = n >> 6, o = n & 63;
    int c = cc*32 + ((lane >> 4) << 3) + j;
    int ky = tap / 3, kx = tap % 3;
    float v = 0.0f;
    if (c < CTOT_){
        if (g == 0)      v = Wf[((o*CTOT_ + c)*3 + ky)*3 + kx];
        else if (g == 1) v = Wi[((o*CTOT_ + c)*3 + ky)*3 + kx];
        else if (g == 2) v = Wc[((o*CTOT_ + c)*3 + ky)*3 + kx];
        else             v = (tap == 4) ? Wo[o*CTOT_ + c] : 0.0f;
    } else if (c == CTOT_ && tap == 4){              // bias channel
        v = (g==0) ? bf[o] : (g==1) ? bi[o] : (g==2) ? bc[o] : bo[o];
    }
    Wfrag[idx] = f2bf(v);
}

// x[b][t][c][y][px] fp32 -> xbf[b][t][y][px][c16] bf16 (vector-stageable)
__global__ void prep_xbf(const float* __restrict__ x, unsigned short* __restrict__ xbf){
    int idx = blockIdx.x*256 + threadIdx.x;          // 524288 = (b,t,y,px) flat
    int px = idx & 63;
    int y  = (idx >> 6) & 63;
    int bt = idx >> 12;
    const float* src = x + (size_t)bt*CIN_*HW_ + y*W_ + px;
    unsigned short tmp[16];
    #pragma unroll
    for (int c = 0; c < 16; ++c) tmp[c] = f2bf(src[(size_t)c*HW_]);
    uint4* dst = (uint4*)(xbf + (size_t)idx*16);
    dst[0] = *(uint4*)(tmp);
    dst[1] = *(uint4*)(tmp + 8);
}

__global__ __launch_bounds__(512, 2) void lstm_step(
    const unsigned short* __restrict__ xbf,
    const unsigned short* __restrict__ Wfrag,
    float* __restrict__ cbuf,                        // [b][y][px][o] fp32, in place
    const unsigned short* __restrict__ hin,          // [b][y][px][o] bf16
    unsigned short* __restrict__ hout,
    float* __restrict__ out,                         // [h|c] std layout, t==15 only
    int t)
{
    __shared__ __align__(16) unsigned short Xs[XS_SIZE];
    const int id   = blockIdx.x;
    // XCD swizzle: id&7 -> XCD; each XCD owns a contiguous 8-row y band so
    // y+-1 halo reads stay XCD-local. 256 blocks = 32/XCD = 1/CU.
    const int xcd  = id & 7;
    const int j    = id >> 3;
    const int b    = j >> 2;
    const int y0   = xcd*8 + ((j & 3) << 1);         // row-pair start
    const int tid  = threadIdx.x;
    const int lane = tid & 63;
    const int wid  = tid >> 6;
    const int wm   = wid >> 2;                       // 0/1: which output row
    const int wn   = wid & 3;                        // N-slice
    const int l15  = lane & 15;
    const int q    = lane >> 4;

    // ---- targeted init (regions disjoint from staged commits -> one barrier)
    uint4 z4; z4.x=z4.y=z4.z=z4.w=0u;
    // P1: every (row,px): zero ch80..95, then bias 1.0 at ch80 (same thread)
    if (tid < 4*XS_ROW){
        unsigned short* p = Xs + (size_t)tid*XS_CH;
        *(uint4*)(p + 80) = z4;
        *(uint4*)(p + 88) = z4;
        p[CTOT_] = 0x3F80;                           // bf16 1.0
    }
    // P2: halo cols px0 & px65, ch0..79: 8 positions x 10 uint4 = 80
    if (tid < 80){
        int pp = tid/10, chunk = tid - pp*10;
        int row = pp >> 1, px = (pp & 1) ? 65 : 0;
        *(uint4*)(Xs + (size_t)(row*XS_ROW + px)*XS_CH + chunk*8) = z4;
    }
    // P3: OOB edge rows (y0==0 -> row0, y0==62 -> row3): px1..64, ch0..79
    if (y0 == 0 || y0 == H_-2){
        int row = (y0 == 0) ? 0 : 3;
        for (int i = tid; i < 640; i += 512){
            int px = 1 + i/10, chunk = i - (i/10)*10;
            *(uint4*)(Xs + (size_t)(row*XS_ROW + px)*XS_CH + chunk*8) = z4;
        }
    }
    // P4: t==0: h region zero, rows 0..3, px1..64, ch16..79 (4/thread)
    if (t == 0){
        #pragma unroll
        for (int k = 0; k < 4; ++k){
            int i = tid + (k << 9);
            int row = i >> 9; int rem = i & 511;
            int px = 1 + (rem >> 3), chunk = rem & 7;
            *(uint4*)(Xs + (size_t)(row*XS_ROW + px)*XS_CH + CIN_ + chunk*8) = z4;
        }
    }

    // ---- stage x: 4 rows x 64 px x 2 ch-chunks = 512 uint4 (exactly 1/thread)
    {
        int row = tid >> 7, rem = tid & 127;
        int px = rem >> 1, ch8 = rem & 1;
        int yy = y0 + row - 1;
        if (yy >= 0 && yy < H_){
            uint4 v = *(const uint4*)(xbf + ((((size_t)(b*T_ + t)*H_ + yy)*W_ + px)*16 + ch8*8));
            *(uint4*)(Xs + ((size_t)(row*XS_ROW + px + 1))*XS_CH + ch8*8) = v;
        }
    }
    // ---- stage h: 4 rows x 64 px x 8 ch-chunks = 2048 uint4 (4/thread)
    if (t > 0){
        #pragma unroll
        for (int k = 0; k < 4; ++k){
            int i = tid + (k << 9);
            int row = i >> 9, rem = i & 511;
            int px = rem >> 3, ch8 = rem & 7;
            int yy = y0 + row - 1;
            if (yy >= 0 && yy < H_){
                uint4 v = *(const uint4*)(hin + ((((size_t)b*H_ + yy)*W_ + px)*HID_ + ch8*8));
                *(uint4*)(Xs + (size_t)(row*XS_ROW + px + 1)*XS_CH + CIN_ + ch8*8) = v;
            }
        }
    }
    __syncthreads();

    // ---- K-loop: 27 tc = tap*3+cc iters, FULLY unrolled, tap-major (linear
    // in Wfrag). A prefetch 2-ahead (LDS ~120cy), B prefetch 3-ahead (L2
    // ~200-300cy). All rotation indices compile-time (full unroll).
    f32x4 acc[4][4];
    #pragma unroll
    for (int g = 0; g < 4; ++g){
        #pragma unroll
        for (int mf = 0; mf < 4; ++mf) acc[g][mf] = (f32x4)0.0f;
    }

    const unsigned short* Abase = Xs + (size_t)(wm*XS_ROW + l15)*XS_CH + q*8;
    const unsigned short* Bbase = Wfrag + (size_t)wn*512 + lane*8;

    short8 a[3][4], bb[4][3], bO[3];
    #pragma unroll
    for (int p = 0; p < 2; ++p){                     // preload A: tc=0,1
        const int tap = p/3, cc = p%3;
        const int ky = tap/3, kx = tap%3;
        const int aoff = (ky*XS_ROW + kx)*XS_CH + cc*32;
        #pragma unroll
        for (int mf = 0; mf < 4; ++mf)
            a[p][mf] = *(const short8*)(Abase + aoff + mf*16*XS_CH);
    }
    #pragma unroll
    for (int p = 0; p < 3; ++p){                     // preload B: tc=0,1,2
        #pragma unroll
        for (int g = 0; g < 3; ++g)
            bb[p][g] = *(const short8*)(Bbase + p*8192 + g*2048);
    }

    #pragma unroll
    for (int tc = 0; tc < 27; ++tc){
        const int tap = tc/3;
        const int ca = tc % 3;                       // A slot
        const int cb = tc % 4;                       // B slot
        if (tc + 2 < 27){                            // A prefetch, distance 2
            const int ntc = tc + 2;
            const int ntap = ntc/3, ncc = ntc%3;
            const int nky = ntap/3, nkx = ntap%3;
            const int aoff = (nky*XS_ROW + nkx)*XS_CH + ncc*32;
            #pragma unroll
            for (int mf = 0; mf < 4; ++mf)
                a[ntc%3][mf] = *(const short8*)(Abase + aoff + mf*16*XS_CH);
        }
        if (tc + 3 < 27){                            // B prefetch, distance 3
            const int ntc = tc + 3;
            #pragma unroll
            for (int g = 0; g < 3; ++g)
                bb[ntc%4][g] = *(const short8*)(Bbase + ntc*8192 + g*2048);
        }
        if (tc >= 9 && tc <= 11)                     // o-gate frags for tc=12..14
            bO[tc-9] = *(const short8*)(Bbase + (tc+3)*8192 + 6144);
        if (tap == 4){  // o-gate: center tap only (ng=12+wn; covers bias ch)
            #pragma unroll
            for (int mf = 0; mf < 4; ++mf)
                acc[3][mf] = __builtin_amdgcn_mfma_f32_16x16x32_bf16(a[ca][mf], bO[tc-12], acc[3][mf], 0,0,0);
        }
        #pragma unroll
        for (int g = 0; g < 3; ++g){
            #pragma unroll
            for (int mf = 0; mf < 4; ++mf)
                acc[g][mf] = __builtin_amdgcn_mfma_f32_16x16x32_bf16(a[ca][mf], bb[cb][g], acc[g][mf], 0,0,0);
        }
    }

    // ---- epilogue: wave-local gates; c in place, channel-last
    const int o = wn*16 + l15;
    const int y = y0 + wm;
    #pragma unroll
    for (int mf = 0; mf < 4; ++mf){
        #pragma unroll
        for (int r = 0; r < 4; ++r){
            const int px = mf*16 + q*4 + r;
            const float fv = sigm_(acc[0][mf][r]);
            const float iv = sigm_(acc[1][mf][r]);
            const float gv = tanh_(acc[2][mf][r]);
            const float ov = sigm_(acc[3][mf][r]);
            const size_t cidx = (((size_t)(b*H_ + y)*W_ + px)*HID_ + o);
            const float cprev = t ? cbuf[cidx] : 0.0f;
            const float cn = cprev*fv + iv*gv;
            const float hn = tanh_(cn)*ov;
            if (t < T_-1){
                cbuf[cidx] = cn;
                hout[cidx] = f2bf(hn);
            } else {
                const size_t oidx = ((((size_t)(b*HID_ + o))*H_ + y)*W_ + px);
                out[oidx] = hn;
                out[CSTRIDE_ + oidx] = cn;
            }
        }
    }
}

extern "C" void kernel_launch(void* const* d_in, const int* in_sizes, int n_in,
                              void* d_out, int out_size, void* d_ws, size_t ws_size,
                              hipStream_t stream){
    const float* x  = (const float*)d_in[0];
    const float* Wf = (const float*)d_in[1];
    const float* bf = (const float*)d_in[2];
    const float* Wi = (const float*)d_in[3];
    const float* bi = (const float*)d_in[4];
    const float* Wc = (const float*)d_in[5];
    const float* bc = (const float*)d_in[6];
    const float* Wo = (const float*)d_in[7];
    const float* bo = (const float*)d_in[8];

    // ws: Wfrag 442368 | xbf 16777216 | cbuf 8388608 | hbfA 4194304 | hbfB 4194304
    unsigned short* Wfrag = (unsigned short*)d_ws;
    unsigned short* xbf   = (unsigned short*)((char*)d_ws + 442368);
    float*          cbuf  = (float*)((char*)d_ws + 442368 + 16777216);
    unsigned short* hbfA  = (unsigned short*)((char*)d_ws + 442368 + 16777216 + 8388608);
    unsigned short* hbfB  = hbfA + CSTRIDE_;

    prep_wfrag<<<dim3(864), dim3(256), 0, stream>>>(Wf, Wi, Wc, Wo, bf, bi, bc, bo, Wfrag);
    prep_xbf<<<dim3(2048), dim3(256), 0, stream>>>(x, xbf);

    for (int t = 0; t < T_; ++t){
        const unsigned short* hi = (t & 1) ? hbfA : hbfB;   // t==0 never reads
        unsigned short*       ho = (t & 1) ? hbfB : hbfA;
        lstm_step<<<dim3(256), dim3(512), 0, stream>>>(
            xbf, Wfrag, cbuf, hi, ho, (float*)d_out, t);
    }
}

// Round 11
// 379.157 us; speedup vs baseline: 2.9915x; 1.0303x over previous
//
#include <hip/hip_runtime.h>

// ConvLSTM B=8,T=16,CIN=16,HID=64,H=W=64,K=3 'SAME' — 16-launch bf16 MFMA.
// Round-14: round-13 base (390.7us best) + ONE change: c-state moves to a
// FRAGMENT-ORDERED private buffer cbuf_frag[block][tid][16] f32.
//  - block<->(b,y0) and tid<->(wm,wn,lane) maps are step-invariant, so the
//    layout is self-consistent across steps (t=0 writes define it).
//  - per-thread c RMW: 64 scalar strided accesses -> 4x global_load_dwordx4
//    + 4x global_store_dwordx4, contiguous 64B/thread, perfectly coalesced.
//  - loads issued INSIDE the K-loop at tc==22 (~5 iters = 400+cy of MFMA
//    cover; spread in time, no round-6-style burst) -> c-load latency no
//    longer exposed after the K-loop.
// Everything else identical to round-13 (targeted init, 2/3-ahead prefetch,
// fully-unrolled tap-major K-loop, 256blk x 512thr).

#define B_ 8
#define T_ 16
#define CIN_ 16
#define HID_ 64
#define H_ 64
#define W_ 64
#define HW_ (H_*W_)
#define CTOT_ 80
#define XS_ROW 66                  // 64 px + 2 halo
#define XS_CH 104                  // 96 K-channels + 8 pad
#define XS_SIZE (4*XS_ROW*XS_CH)   // 27456 hw = 54912 B
#define CSTRIDE_ (B_*HID_*HW_)     // 2097152

typedef __attribute__((ext_vector_type(8))) short short8;
typedef __attribute__((ext_vector_type(4))) float f32x4;

__device__ __forceinline__ unsigned short f2bf(float f){
    unsigned u = __float_as_uint(f);
    u = (u + 0x7FFFu + ((u >> 16) & 1u)) >> 16;   // RNE
    return (unsigned short)u;
}
__device__ __forceinline__ float sigm_(float v){ return 1.0f/(1.0f + __expf(-v)); }
__device__ __forceinline__ float tanh_(float v){ return 2.0f/(1.0f + __expf(-2.0f*v)) - 1.0f; }

// Wfrag: [tap 9][cc 3][ng 16] frags of 512 hw ([lane][j]).
// n = ng*16+(lane&15): g=n>>6, o=n&63; k-ch c = cc*32+(lane>>4)*8+j.
// Bias folded at c==80 (constant-1 A channel), center tap only.
__global__ void prep_wfrag(const float* __restrict__ Wf, const float* __restrict__ Wi,
                           const float* __restrict__ Wc, const float* __restrict__ Wo,
                           const float* __restrict__ bf, const float* __restrict__ bi,
                           const float* __restrict__ bc, const float* __restrict__ bo,
                           unsigned short* __restrict__ Wfrag){
    int idx = blockIdx.x*256 + threadIdx.x;          // 864*256 = 221184 exact
    int j    = idx & 7;
    int lane = (idx >> 3) & 63;
    int frag = idx >> 9;
    int ng = frag & 15;
    int tc = frag >> 4;
    int cc = tc % 3, tap = tc / 3;
    int n = ng*16 + (lane & 15);
    int g = n >> 6, o = n & 63;
    int c = cc*32 + ((lane >> 4) << 3) + j;
    int ky = tap / 3, kx = tap % 3;
    float v = 0.0f;
    if (c < CTOT_){
        if (g == 0)      v = Wf[((o*CTOT_ + c)*3 + ky)*3 + kx];
        else if (g == 1) v = Wi[((o*CTOT_ + c)*3 + ky)*3 + kx];
        else if (g == 2) v = Wc[((o*CTOT_ + c)*3 + ky)*3 + kx];
        else             v = (tap == 4) ? Wo[o*CTOT_ + c] : 0.0f;
    } else if (c == CTOT_ && tap == 4){              // bias channel
        v = (g==0) ? bf[o] : (g==1) ? bi[o] : (g==2) ? bc[o] : bo[o];
    }
    Wfrag[idx] = f2bf(v);
}

// x[b][t][c][y][px] fp32 -> xbf[b][t][y][px][c16] bf16 (vector-stageable)
__global__ void prep_xbf(const float* __restrict__ x, unsigned short* __restrict__ xbf){
    int idx = blockIdx.x*256 + threadIdx.x;          // 524288 = (b,t,y,px) flat
    int px = idx & 63;
    int y  = (idx >> 6) & 63;
    int bt = idx >> 12;
    const float* src = x + (size_t)bt*CIN_*HW_ + y*W_ + px;
    unsigned short tmp[16];
    #pragma unroll
    for (int c = 0; c < 16; ++c) tmp[c] = f2bf(src[(size_t)c*HW_]);
    uint4* dst = (uint4*)(xbf + (size_t)idx*16);
    dst[0] = *(uint4*)(tmp);
    dst[1] = *(uint4*)(tmp + 8);
}

__global__ __launch_bounds__(512, 2) void lstm_step(
    const unsigned short* __restrict__ xbf,
    const unsigned short* __restrict__ Wfrag,
    float* __restrict__ cbuf,                        // FRAGMENT layout [blk][tid][16]
    const unsigned short* __restrict__ hin,          // [b][y][px][o] bf16
    unsigned short* __restrict__ hout,
    float* __restrict__ out,                         // [h|c] std layout, t==15 only
    int t)
{
    __shared__ __align__(16) unsigned short Xs[XS_SIZE];
    const int id   = blockIdx.x;
    // XCD swizzle: id&7 -> XCD; each XCD owns a contiguous 8-row y band so
    // y+-1 halo reads stay XCD-local. 256 blocks = 32/XCD = 1/CU.
    const int xcd  = id & 7;
    const int j    = id >> 3;
    const int b    = j >> 2;
    const int y0   = xcd*8 + ((j & 3) << 1);         // row-pair start
    const int tid  = threadIdx.x;
    const int lane = tid & 63;
    const int wid  = tid >> 6;
    const int wm   = wid >> 2;                       // 0/1: which output row
    const int wn   = wid & 3;                        // N-slice
    const int l15  = lane & 15;
    const int q    = lane >> 4;

    // ---- targeted init (regions disjoint from staged commits -> one barrier)
    uint4 z4; z4.x=z4.y=z4.z=z4.w=0u;
    // P1: every (row,px): zero ch80..95, then bias 1.0 at ch80 (same thread)
    if (tid < 4*XS_ROW){
        unsigned short* p = Xs + (size_t)tid*XS_CH;
        *(uint4*)(p + 80) = z4;
        *(uint4*)(p + 88) = z4;
        p[CTOT_] = 0x3F80;                           // bf16 1.0
    }
    // P2: halo cols px0 & px65, ch0..79: 8 positions x 10 uint4 = 80
    if (tid < 80){
        int pp = tid/10, chunk = tid - pp*10;
        int row = pp >> 1, px = (pp & 1) ? 65 : 0;
        *(uint4*)(Xs + (size_t)(row*XS_ROW + px)*XS_CH + chunk*8) = z4;
    }
    // P3: OOB edge rows (y0==0 -> row0, y0==62 -> row3): px1..64, ch0..79
    if (y0 == 0 || y0 == H_-2){
        int row = (y0 == 0) ? 0 : 3;
        for (int i = tid; i < 640; i += 512){
            int px = 1 + i/10, chunk = i - (i/10)*10;
            *(uint4*)(Xs + (size_t)(row*XS_ROW + px)*XS_CH + chunk*8) = z4;
        }
    }
    // P4: t==0: h region zero, rows 0..3, px1..64, ch16..79 (4/thread)
    if (t == 0){
        #pragma unroll
        for (int k = 0; k < 4; ++k){
            int i = tid + (k << 9);
            int row = i >> 9; int rem = i & 511;
            int px = 1 + (rem >> 3), chunk = rem & 7;
            *(uint4*)(Xs + (size_t)(row*XS_ROW + px)*XS_CH + CIN_ + chunk*8) = z4;
        }
    }

    // ---- stage x: 4 rows x 64 px x 2 ch-chunks = 512 uint4 (exactly 1/thread)
    {
        int row = tid >> 7, rem = tid & 127;
        int px = rem >> 1, ch8 = rem & 1;
        int yy = y0 + row - 1;
        if (yy >= 0 && yy < H_){
            uint4 v = *(const uint4*)(xbf + ((((size_t)(b*T_ + t)*H_ + yy)*W_ + px)*16 + ch8*8));
            *(uint4*)(Xs + ((size_t)(row*XS_ROW + px + 1))*XS_CH + ch8*8) = v;
        }
    }
    // ---- stage h: 4 rows x 64 px x 8 ch-chunks = 2048 uint4 (4/thread)
    if (t > 0){
        #pragma unroll
        for (int k = 0; k < 4; ++k){
            int i = tid + (k << 9);
            int row = i >> 9, rem = i & 511;
            int px = rem >> 3, ch8 = rem & 7;
            int yy = y0 + row - 1;
            if (yy >= 0 && yy < H_){
                uint4 v = *(const uint4*)(hin + ((((size_t)b*H_ + yy)*W_ + px)*HID_ + ch8*8));
                *(uint4*)(Xs + (size_t)(row*XS_ROW + px + 1)*XS_CH + CIN_ + ch8*8) = v;
            }
        }
    }
    __syncthreads();

    // ---- K-loop: 27 tc = tap*3+cc iters, FULLY unrolled, tap-major (linear
    // in Wfrag). A prefetch 2-ahead (LDS ~120cy), B prefetch 3-ahead (L2
    // ~200-300cy). c-fragment loads issued at tc==22 (~5 iters of cover).
    f32x4 acc[4][4];
    #pragma unroll
    for (int g = 0; g < 4; ++g){
        #pragma unroll
        for (int mf = 0; mf < 4; ++mf) acc[g][mf] = (f32x4)0.0f;
    }

    const unsigned short* Abase = Xs + (size_t)(wm*XS_ROW + l15)*XS_CH + q*8;
    const unsigned short* Bbase = Wfrag + (size_t)wn*512 + lane*8;
    float* cfr = cbuf + ((size_t)id << 13) + ((size_t)tid << 4);  // [blk][tid][16]

    short8 a[3][4], bb[4][3], bO[3];
    f32x4 cp[4];
    #pragma unroll
    for (int p = 0; p < 2; ++p){                     // preload A: tc=0,1
        const int tap = p/3, cc = p%3;
        const int ky = tap/3, kx = tap%3;
        const int aoff = (ky*XS_ROW + kx)*XS_CH + cc*32;
        #pragma unroll
        for (int mf = 0; mf < 4; ++mf)
            a[p][mf] = *(const short8*)(Abase + aoff + mf*16*XS_CH);
    }
    #pragma unroll
    for (int p = 0; p < 3; ++p){                     // preload B: tc=0,1,2
        #pragma unroll
        for (int g = 0; g < 3; ++g)
            bb[p][g] = *(const short8*)(Bbase + p*8192 + g*2048);
    }

    #pragma unroll
    for (int tc = 0; tc < 27; ++tc){
        const int tap = tc/3;
        const int ca = tc % 3;                       // A slot
        const int cb = tc % 4;                       // B slot
        if (tc + 2 < 27){                            // A prefetch, distance 2
            const int ntc = tc + 2;
            const int ntap = ntc/3, ncc = ntc%3;
            const int nky = ntap/3, nkx = ntap%3;
            const int aoff = (nky*XS_ROW + nkx)*XS_CH + ncc*32;
            #pragma unroll
            for (int mf = 0; mf < 4; ++mf)
                a[ntc%3][mf] = *(const short8*)(Abase + aoff + mf*16*XS_CH);
        }
        if (tc + 3 < 27){                            // B prefetch, distance 3
            const int ntc = tc + 3;
            #pragma unroll
            for (int g = 0; g < 3; ++g)
                bb[ntc%4][g] = *(const short8*)(Bbase + ntc*8192 + g*2048);
        }
        if (tc >= 9 && tc <= 11)                     // o-gate frags for tc=12..14
            bO[tc-9] = *(const short8*)(Bbase + (tc+3)*8192 + 6144);
        if (tc == 22 && t > 0){                      // c-fragment prefetch
            #pragma unroll
            for (int mf = 0; mf < 4; ++mf)
                cp[mf] = *(const f32x4*)(cfr + mf*4);
        }
        if (tap == 4){  // o-gate: center tap only (ng=12+wn; covers bias ch)
            #pragma unroll
            for (int mf = 0; mf < 4; ++mf)
                acc[3][mf] = __builtin_amdgcn_mfma_f32_16x16x32_bf16(a[ca][mf], bO[tc-12], acc[3][mf], 0,0,0);
        }
        #pragma unroll
        for (int g = 0; g < 3; ++g){
            #pragma unroll
            for (int mf = 0; mf < 4; ++mf)
                acc[g][mf] = __builtin_amdgcn_mfma_f32_16x16x32_bf16(a[ca][mf], bb[cb][g], acc[g][mf], 0,0,0);
        }
    }

    // ---- epilogue: wave-local gates; c in fragment layout, h channel-last
    const int o = wn*16 + l15;
    const int y = y0 + wm;
    #pragma unroll
    for (int mf = 0; mf < 4; ++mf){
        f32x4 cnv;
        #pragma unroll
        for (int r = 0; r < 4; ++r){
            const int px = mf*16 + q*4 + r;
            const float fv = sigm_(acc[0][mf][r]);
            const float iv = sigm_(acc[1][mf][r]);
            const float gv = tanh_(acc[2][mf][r]);
            const float ov = sigm_(acc[3][mf][r]);
            const float cprev = t ? cp[mf][r] : 0.0f;
            const float cn = cprev*fv + iv*gv;
            const float hn = tanh_(cn)*ov;
            cnv[r] = cn;
            if (t < T_-1){
                hout[(((size_t)(b*H_ + y)*W_ + px)*HID_ + o)] = f2bf(hn);
            } else {
                const size_t oidx = ((((size_t)(b*HID_ + o))*H_ + y)*W_ + px);
                out[oidx] = hn;
                out[CSTRIDE_ + oidx] = cn;
            }
        }
        if (t < T_-1) *(f32x4*)(cfr + mf*4) = cnv;   // 16B vector c store
    }
}

extern "C" void kernel_launch(void* const* d_in, const int* in_sizes, int n_in,
                              void* d_out, int out_size, void* d_ws, size_t ws_size,
                              hipStream_t stream){
    const float* x  = (const float*)d_in[0];
    const float* Wf = (const float*)d_in[1];
    const float* bf = (const float*)d_in[2];
    const float* Wi = (const float*)d_in[3];
    const float* bi = (const float*)d_in[4];
    const float* Wc = (const float*)d_in[5];
    const float* bc = (const float*)d_in[6];
    const float* Wo = (const float*)d_in[7];
    const float* bo = (const float*)d_in[8];

    // ws: Wfrag 442368 | xbf 16777216 | cbuf_frag 8388608 | hbfA | hbfB
    unsigned short* Wfrag = (unsigned short*)d_ws;
    unsigned short* xbf   = (unsigned short*)((char*)d_ws + 442368);
    float*          cbuf  = (float*)((char*)d_ws + 442368 + 16777216);
    unsigned short* hbfA  = (unsigned short*)((char*)d_ws + 442368 + 16777216 + 8388608);
    unsigned short* hbfB  = hbfA + CSTRIDE_;

    prep_wfrag<<<dim3(864), dim3(256), 0, stream>>>(Wf, Wi, Wc, Wo, bf, bi, bc, bo, Wfrag);
    prep_xbf<<<dim3(2048), dim3(256), 0, stream>>>(x, xbf);

    for (int t = 0; t < T_; ++t){
        const unsigned short* hi = (t & 1) ? hbfA : hbfB;   // t==0 never reads
        unsigned short*       ho = (t & 1) ? hbfB : hbfA;
        lstm_step<<<dim3(256), dim3(512), 0, stream>>>(
            xbf, Wfrag, cbuf, hi, ho, (float*)d_out, t);
    }
}

// Round 12
// 376.262 us; speedup vs baseline: 3.0145x; 1.0077x over previous
//
#include <hip/hip_runtime.h>

// ConvLSTM B=8,T=16,CIN=16,HID=64,H=W=64,K=3 'SAME' — 16-launch bf16 MFMA.
// Round-15: round-14 base (379us best) + ONE change: kill the 4-way LDS bank
// conflict on A-fragment ds_read_b128 (SQ_LDS_BANK_CONFLICT 907K/dispatch).
// Old layout XS_CH=104: first-bank = (20*l15+4q) mod 32 -> 4-way clusters
// {(l,q),(l+2,q-2),(l+8,q),(l+10,q-2)} = ~4 extra cy per read on the
// A->MFMA chain. New: XS_CH=128 hw (row stride 256B = 16 granules, == 0 mod
// 8) + T2 XOR swizzle granule' = granule ^ (pos&7) applied on BOTH staging
// writes and reads (rule #21). Bank-group = granule' (XOR bijection) ->
// exactly 8 lanes per 4-bank cluster for every (cc,q): uniform, conflict-
// free. pos+16*mf preserves pos&7 so per-mf offsets stay +2048 constants.
// LDS 67.6KB; 2 blocks/CU = 135KB <= 160KB (occupancy unchanged). Chunks
// 12..15 never read -> never initialized.

#define B_ 8
#define T_ 16
#define CIN_ 16
#define HID_ 64
#define H_ 64
#define W_ 64
#define HW_ (H_*W_)
#define CTOT_ 80
#define XS_ROW 66                  // 64 px + 2 halo (positions per row)
#define XS_CH 128                  // 16 granules of 16B; 12 used, 4 dead
#define XS_SIZE (4*XS_ROW*XS_CH)   // 33792 hw = 67584 B
#define CSTRIDE_ (B_*HID_*HW_)     // 2097152

typedef __attribute__((ext_vector_type(8))) short short8;
typedef __attribute__((ext_vector_type(4))) float f32x4;

__device__ __forceinline__ unsigned short f2bf(float f){
    unsigned u = __float_as_uint(f);
    u = (u + 0x7FFFu + ((u >> 16) & 1u)) >> 16;   // RNE
    return (unsigned short)u;
}
__device__ __forceinline__ float sigm_(float v){ return 1.0f/(1.0f + __expf(-v)); }
__device__ __forceinline__ float tanh_(float v){ return 2.0f/(1.0f + __expf(-2.0f*v)) - 1.0f; }
// swizzled hw-index of 16B-granule `chunk` at position `pos`
__device__ __forceinline__ int xsw(int pos, int chunk){
    return (pos << 7) + (((chunk ^ pos) & 7) << 3) + ((chunk & 8) << 3);
}

// Wfrag: [tap 9][cc 3][ng 16] frags of 512 hw ([lane][j]).
// n = ng*16+(lane&15): g=n>>6, o=n&63; k-ch c = cc*32+(lane>>4)*8+j.
// Bias folded at c==80 (constant-1 A channel), center tap only.
__global__ void prep_wfrag(const float* __restrict__ Wf, const float* __restrict__ Wi,
                           const float* __restrict__ Wc, const float* __restrict__ Wo,
                           const float* __restrict__ bf, const float* __restrict__ bi,
                           const float* __restrict__ bc, const float* __restrict__ bo,
                           unsigned short* __restrict__ Wfrag){
    int idx = blockIdx.x*256 + threadIdx.x;          // 864*256 = 221184 exact
    int j    = idx & 7;
    int lane = (idx >> 3) & 63;
    int frag = idx >> 9;
    int ng = frag & 15;
    int tc = frag >> 4;
    int cc = tc % 3, tap = tc / 3;
    int n = ng*16 + (lane & 15);
    int g = n >> 6, o = n & 63;
    int c = cc*32 + ((lane >> 4) << 3) + j;
    int ky = tap / 3, kx = tap % 3;
    float v = 0.0f;
    if (c < CTOT_){
        if (g == 0)      v = Wf[((o*CTOT_ + c)*3 + ky)*3 + kx];
        else if (g == 1) v = Wi[((o*CTOT_ + c)*3 + ky)*3 + kx];
        else if (g == 2) v = Wc[((o*CTOT_ + c)*3 + ky)*3 + kx];
        else             v = (tap == 4) ? Wo[o*CTOT_ + c] : 0.0f;
    } else if (c == CTOT_ && tap == 4){              // bias channel
        v = (g==0) ? bf[o] : (g==1) ? bi[o] : (g==2) ? bc[o] : bo[o];
    }
    Wfrag[idx] = f2bf(v);
}

// x[b][t][c][y][px] fp32 -> xbf[b][t][y][px][c16] bf16 (vector-stageable)
__global__ void prep_xbf(const float* __restrict__ x, unsigned short* __restrict__ xbf){
    int idx = blockIdx.x*256 + threadIdx.x;          // 524288 = (b,t,y,px) flat
    int px = idx & 63;
    int y  = (idx >> 6) & 63;
    int bt = idx >> 12;
    const float* src = x + (size_t)bt*CIN_*HW_ + y*W_ + px;
    unsigned short tmp[16];
    #pragma unroll
    for (int c = 0; c < 16; ++c) tmp[c] = f2bf(src[(size_t)c*HW_]);
    uint4* dst = (uint4*)(xbf + (size_t)idx*16);
    dst[0] = *(uint4*)(tmp);
    dst[1] = *(uint4*)(tmp + 8);
}

__global__ __launch_bounds__(512, 2) void lstm_step(
    const unsigned short* __restrict__ xbf,
    const unsigned short* __restrict__ Wfrag,
    float* __restrict__ cbuf,                        // FRAGMENT layout [blk][tid][16]
    const unsigned short* __restrict__ hin,          // [b][y][px][o] bf16
    unsigned short* __restrict__ hout,
    float* __restrict__ out,                         // [h|c] std layout, t==15 only
    int t)
{
    __shared__ __align__(16) unsigned short Xs[XS_SIZE];
    const int id   = blockIdx.x;
    // XCD swizzle: id&7 -> XCD; each XCD owns a contiguous 8-row y band so
    // y+-1 halo reads stay XCD-local. 256 blocks = 32/XCD = 1/CU.
    const int xcd  = id & 7;
    const int j    = id >> 3;
    const int b    = j >> 2;
    const int y0   = xcd*8 + ((j & 3) << 1);         // row-pair start
    const int tid  = threadIdx.x;
    const int lane = tid & 63;
    const int wid  = tid >> 6;
    const int wm   = wid >> 2;                       // 0/1: which output row
    const int wn   = wid & 3;                        // N-slice
    const int l15  = lane & 15;
    const int q    = lane >> 4;

    // ---- targeted init (regions disjoint from staged commits -> one barrier)
    uint4 z4; z4.x=z4.y=z4.z=z4.w=0u;
    // P1: every pos: zero chunks 10,11 (hw 80..95), then bias 1.0 at hw 80
    if (tid < 4*XS_ROW){
        *(uint4*)(Xs + xsw(tid, 10)) = z4;
        *(uint4*)(Xs + xsw(tid, 11)) = z4;
        Xs[xsw(tid, 10)] = 0x3F80;                   // bf16 1.0 (chunk10 byte0)
    }
    // P2: halo cols px0 & px65, chunks 0..11: 8 positions x 12 = 96
    if (tid < 96){
        int pp = tid/12, ch = tid - pp*12;
        int row = pp >> 1, px = (pp & 1) ? 65 : 0;
        *(uint4*)(Xs + xsw(row*XS_ROW + px, ch)) = z4;
    }
    // P3: OOB edge rows (y0==0 -> row0, y0==62 -> row3): px1..64, chunks 0..11
    if (y0 == 0 || y0 == H_-2){
        int row = (y0 == 0) ? 0 : 3;
        for (int i = tid; i < 768; i += 512){
            int px = 1 + i/12, ch = i - (i/12)*12;
            *(uint4*)(Xs + xsw(row*XS_ROW + px, ch)) = z4;
        }
    }
    // P4: t==0: h region zero, rows 0..3, px1..64, chunks 2..9 (4/thread)
    if (t == 0){
        #pragma unroll
        for (int k = 0; k < 4; ++k){
            int i = tid + (k << 9);
            int row = i >> 9; int rem = i & 511;
            int px = 1 + (rem >> 3), ch8 = rem & 7;
            *(uint4*)(Xs + xsw(row*XS_ROW + px, 2 + ch8)) = z4;
        }
    }

    // ---- stage x: 4 rows x 64 px x 2 chunks = 512 uint4 (exactly 1/thread)
    {
        int row = tid >> 7, rem = tid & 127;
        int px = rem >> 1, ch8 = rem & 1;
        int yy = y0 + row - 1;
        if (yy >= 0 && yy < H_){
            uint4 v = *(const uint4*)(xbf + ((((size_t)(b*T_ + t)*H_ + yy)*W_ + px)*16 + ch8*8));
            *(uint4*)(Xs + xsw(row*XS_ROW + px + 1, ch8)) = v;
        }
    }
    // ---- stage h: 4 rows x 64 px x 8 chunks = 2048 uint4 (4/thread)
    if (t > 0){
        #pragma unroll
        for (int k = 0; k < 4; ++k){
            int i = tid + (k << 9);
            int row = i >> 9, rem = i & 511;
            int px = rem >> 3, ch8 = rem & 7;
            int yy = y0 + row - 1;
            if (yy >= 0 && yy < H_){
                uint4 v = *(const uint4*)(hin + ((((size_t)b*H_ + yy)*W_ + px)*HID_ + ch8*8));
                *(uint4*)(Xs + xsw(row*XS_ROW + px + 1, 2 + ch8)) = v;
            }
        }
    }
    __syncthreads();

    // ---- K-loop: 27 tc = tap*3+cc iters, FULLY unrolled, tap-major (linear
    // in Wfrag). A prefetch 2-ahead, B 3-ahead, c-frag loads at tc==22.
    // A granule = (cc*4+q) ^ (pos&7): conflict-free (8 lanes/bank-cluster).
    f32x4 acc[4][4];
    #pragma unroll
    for (int g = 0; g < 4; ++g){
        #pragma unroll
        for (int mf = 0; mf < 4; ++mf) acc[g][mf] = (f32x4)0.0f;
    }

    const int posA = wm*XS_ROW + l15;                // + (ky*66+kx) const per tc
    const unsigned short* Bbase = Wfrag + (size_t)wn*512 + lane*8;
    float* cfr = cbuf + ((size_t)id << 13) + ((size_t)tid << 4);  // [blk][tid][16]

    short8 a[3][4], bb[4][3], bO[3];
    f32x4 cp[4];
    #pragma unroll
    for (int p = 0; p < 2; ++p){                     // preload A: tc=0,1
        const int tap = p/3, cc = p%3;
        const int pos = posA + (tap/3)*XS_ROW + (tap%3);
        const int ad = xsw(pos, cc*4 + q);
        #pragma unroll
        for (int mf = 0; mf < 4; ++mf)
            a[p][mf] = *(const short8*)(Xs + ad + mf*16*XS_CH);
    }
    #pragma unroll
    for (int p = 0; p < 3; ++p){                     // preload B: tc=0,1,2
        #pragma unroll
        for (int g = 0; g < 3; ++g)
            bb[p][g] = *(const short8*)(Bbase + p*8192 + g*2048);
    }

    #pragma unroll
    for (int tc = 0; tc < 27; ++tc){
        const int tap = tc/3;
        const int ca = tc % 3;                       // A slot
        const int cb = tc % 4;                       // B slot
        if (tc + 2 < 27){                            // A prefetch, distance 2
            const int ntc = tc + 2;
            const int ntap = ntc/3, ncc = ntc%3;
            const int pos = posA + (ntap/3)*XS_ROW + (ntap%3);
            const int ad = xsw(pos, ncc*4 + q);
            #pragma unroll
            for (int mf = 0; mf < 4; ++mf)
                a[ntc%3][mf] = *(const short8*)(Xs + ad + mf*16*XS_CH);
        }
        if (tc + 3 < 27){                            // B prefetch, distance 3
            const int ntc = tc + 3;
            #pragma unroll
            for (int g = 0; g < 3; ++g)
                bb[ntc%4][g] = *(const short8*)(Bbase + ntc*8192 + g*2048);
        }
        if (tc >= 9 && tc <= 11)                     // o-gate frags for tc=12..14
            bO[tc-9] = *(const short8*)(Bbase + (tc+3)*8192 + 6144);
        if (tc == 22 && t > 0){                      // c-fragment prefetch
            #pragma unroll
            for (int mf = 0; mf < 4; ++mf)
                cp[mf] = *(const f32x4*)(cfr + mf*4);
        }
        if (tap == 4){  // o-gate: center tap only (ng=12+wn; covers bias ch)
            #pragma unroll
            for (int mf = 0; mf < 4; ++mf)
                acc[3][mf] = __builtin_amdgcn_mfma_f32_16x16x32_bf16(a[ca][mf], bO[tc-12], acc[3][mf], 0,0,0);
        }
        #pragma unroll
        for (int g = 0; g < 3; ++g){
            #pragma unroll
            for (int mf = 0; mf < 4; ++mf)
                acc[g][mf] = __builtin_amdgcn_mfma_f32_16x16x32_bf16(a[ca][mf], bb[cb][g], acc[g][mf], 0,0,0);
        }
    }

    // ---- epilogue: wave-local gates; c in fragment layout, h channel-last
    const int o = wn*16 + l15;
    const int y = y0 + wm;
    #pragma unroll
    for (int mf = 0; mf < 4; ++mf){
        f32x4 cnv;
        #pragma unroll
        for (int r = 0; r < 4; ++r){
            const int px = mf*16 + q*4 + r;
            const float fv = sigm_(acc[0][mf][r]);
            const float iv = sigm_(acc[1][mf][r]);
            const float gv = tanh_(acc[2][mf][r]);
            const float ov = sigm_(acc[3][mf][r]);
            const float cprev = t ? cp[mf][r] : 0.0f;
            const float cn = cprev*fv + iv*gv;
            const float hn = tanh_(cn)*ov;
            cnv[r] = cn;
            if (t < T_-1){
                hout[(((size_t)(b*H_ + y)*W_ + px)*HID_ + o)] = f2bf(hn);
            } else {
                const size_t oidx = ((((size_t)(b*HID_ + o))*H_ + y)*W_ + px);
                out[oidx] = hn;
                out[CSTRIDE_ + oidx] = cn;
            }
        }
        if (t < T_-1) *(f32x4*)(cfr + mf*4) = cnv;   // 16B vector c store
    }
}

extern "C" void kernel_launch(void* const* d_in, const int* in_sizes, int n_in,
                              void* d_out, int out_size, void* d_ws, size_t ws_size,
                              hipStream_t stream){
    const float* x  = (const float*)d_in[0];
    const float* Wf = (const float*)d_in[1];
    const float* bf = (const float*)d_in[2];
    const float* Wi = (const float*)d_in[3];
    const float* bi = (const float*)d_in[4];
    const float* Wc = (const float*)d_in[5];
    const float* bc = (const float*)d_in[6];
    const float* Wo = (const float*)d_in[7];
    const float* bo = (const float*)d_in[8];

    // ws: Wfrag 442368 | xbf 16777216 | cbuf_frag 8388608 | hbfA | hbfB
    unsigned short* Wfrag = (unsigned short*)d_ws;
    unsigned short* xbf   = (unsigned short*)((char*)d_ws + 442368);
    float*          cbuf  = (float*)((char*)d_ws + 442368 + 16777216);
    unsigned short* hbfA  = (unsigned short*)((char*)d_ws + 442368 + 16777216 + 8388608);
    unsigned short* hbfB  = hbfA + CSTRIDE_;

    prep_wfrag<<<dim3(864), dim3(256), 0, stream>>>(Wf, Wi, Wc, Wo, bf, bi, bc, bo, Wfrag);
    prep_xbf<<<dim3(2048), dim3(256), 0, stream>>>(x, xbf);

    for (int t = 0; t < T_; ++t){
        const unsigned short* hi = (t & 1) ? hbfA : hbfB;   // t==0 never reads
        unsigned short*       ho = (t & 1) ? hbfB : hbfA;
        lstm_step<<<dim3(256), dim3(512), 0, stream>>>(
            xbf, Wfrag, cbuf, hi, ho, (float*)d_out, t);
    }
}

// Round 13
// 369.968 us; speedup vs baseline: 3.0658x; 1.0170x over previous
//
#include <hip/hip_runtime.h>

// ConvLSTM B=8,T=16,CIN=16,HID=64,H=W=64,K=3 'SAME' — 16-launch bf16 MFMA.
// Round-16: round-15 base (376.3us best) + ONE change: merge prep_wfrag and
// prep_xbf into a single 2912-block kernel (they are independent but were
// serialized on the stream: ~4-5us of exec+gap). lstm_step is UNTOUCHED.
// Floor model (if this lands ~376 within noise, structure is done):
//   376 = prep(~20) + 16 x 22.3us, per-step = launch/drain 3-5 + staging
//   critical path ~8 + K-loop latency ~8 + epilogue ~2. All structural
//   alternatives measured worse: persistent+fence +190% (L2 wb/inv kills
//   Wfrag residency), 512blk +60% (L2 thrash), 16-wave +13% (2x B-issue),
//   M_wave=32 +7%. Register floor (acc 64 + ~100 operand regs) pins
//   occupancy at 2-3 waves/SIMD; multi-stream batch parallelism illegal
//   under graph capture; 2-step fusion loses to halo-overhead x grid-size.

#define B_ 8
#define T_ 16
#define CIN_ 16
#define HID_ 64
#define H_ 64
#define W_ 64
#define HW_ (H_*W_)
#define CTOT_ 80
#define XS_ROW 66                  // 64 px + 2 halo (positions per row)
#define XS_CH 128                  // 16 granules of 16B; 12 used, 4 dead
#define XS_SIZE (4*XS_ROW*XS_CH)   // 33792 hw = 67584 B
#define CSTRIDE_ (B_*HID_*HW_)     // 2097152

typedef __attribute__((ext_vector_type(8))) short short8;
typedef __attribute__((ext_vector_type(4))) float f32x4;

__device__ __forceinline__ unsigned short f2bf(float f){
    unsigned u = __float_as_uint(f);
    u = (u + 0x7FFFu + ((u >> 16) & 1u)) >> 16;   // RNE
    return (unsigned short)u;
}
__device__ __forceinline__ float sigm_(float v){ return 1.0f/(1.0f + __expf(-v)); }
__device__ __forceinline__ float tanh_(float v){ return 2.0f/(1.0f + __expf(-2.0f*v)) - 1.0f; }
// swizzled hw-index of 16B-granule `chunk` at position `pos`
__device__ __forceinline__ int xsw(int pos, int chunk){
    return (pos << 7) + (((chunk ^ pos) & 7) << 3) + ((chunk & 8) << 3);
}

// Merged prep: blocks 0..863 build Wfrag; blocks 864..2911 convert x->xbf.
// Wfrag: [tap 9][cc 3][ng 16] frags of 512 hw ([lane][j]).
// n = ng*16+(lane&15): g=n>>6, o=n&63; k-ch c = cc*32+(lane>>4)*8+j.
// Bias folded at c==80 (constant-1 A channel), center tap only.
__global__ void prep_all(const float* __restrict__ x,
                         const float* __restrict__ Wf, const float* __restrict__ Wi,
                         const float* __restrict__ Wc, const float* __restrict__ Wo,
                         const float* __restrict__ bf, const float* __restrict__ bi,
                         const float* __restrict__ bc, const float* __restrict__ bo,
                         unsigned short* __restrict__ Wfrag,
                         unsigned short* __restrict__ xbf){
    if (blockIdx.x < 864){
        int idx = blockIdx.x*256 + threadIdx.x;      // 864*256 = 221184 exact
        int j    = idx & 7;
        int lane = (idx >> 3) & 63;
        int frag = idx >> 9;
        int ng = frag & 15;
        int tc = frag >> 4;
        int cc = tc % 3, tap = tc / 3;
        int n = ng*16 + (lane & 15);
        int g = n >> 6, o = n & 63;
        int c = cc*32 + ((lane >> 4) << 3) + j;
        int ky = tap / 3, kx = tap % 3;
        float v = 0.0f;
        if (c < CTOT_){
            if (g == 0)      v = Wf[((o*CTOT_ + c)*3 + ky)*3 + kx];
            else if (g == 1) v = Wi[((o*CTOT_ + c)*3 + ky)*3 + kx];
            else if (g == 2) v = Wc[((o*CTOT_ + c)*3 + ky)*3 + kx];
            else             v = (tap == 4) ? Wo[o*CTOT_ + c] : 0.0f;
        } else if (c == CTOT_ && tap == 4){          // bias channel
            v = (g==0) ? bf[o] : (g==1) ? bi[o] : (g==2) ? bc[o] : bo[o];
        }
        Wfrag[idx] = f2bf(v);
    } else {
        // x[b][t][c][y][px] fp32 -> xbf[b][t][y][px][c16] bf16
        int idx = (blockIdx.x - 864)*256 + threadIdx.x;  // 524288 = (b,t,y,px)
        int px = idx & 63;
        int y  = (idx >> 6) & 63;
        int bt = idx >> 12;
        const float* src = x + (size_t)bt*CIN_*HW_ + y*W_ + px;
        unsigned short tmp[16];
        #pragma unroll
        for (int c = 0; c < 16; ++c) tmp[c] = f2bf(src[(size_t)c*HW_]);
        uint4* dst = (uint4*)(xbf + (size_t)idx*16);
        dst[0] = *(uint4*)(tmp);
        dst[1] = *(uint4*)(tmp + 8);
    }
}

__global__ __launch_bounds__(512, 2) void lstm_step(
    const unsigned short* __restrict__ xbf,
    const unsigned short* __restrict__ Wfrag,
    float* __restrict__ cbuf,                        // FRAGMENT layout [blk][tid][16]
    const unsigned short* __restrict__ hin,          // [b][y][px][o] bf16
    unsigned short* __restrict__ hout,
    float* __restrict__ out,                         // [h|c] std layout, t==15 only
    int t)
{
    __shared__ __align__(16) unsigned short Xs[XS_SIZE];
    const int id   = blockIdx.x;
    // XCD swizzle: id&7 -> XCD; each XCD owns a contiguous 8-row y band so
    // y+-1 halo reads stay XCD-local. 256 blocks = 32/XCD = 1/CU.
    const int xcd  = id & 7;
    const int j    = id >> 3;
    const int b    = j >> 2;
    const int y0   = xcd*8 + ((j & 3) << 1);         // row-pair start
    const int tid  = threadIdx.x;
    const int lane = tid & 63;
    const int wid  = tid >> 6;
    const int wm   = wid >> 2;                       // 0/1: which output row
    const int wn   = wid & 3;                        // N-slice
    const int l15  = lane & 15;
    const int q    = lane >> 4;

    // ---- targeted init (regions disjoint from staged commits -> one barrier)
    uint4 z4; z4.x=z4.y=z4.z=z4.w=0u;
    // P1: every pos: zero chunks 10,11 (hw 80..95), then bias 1.0 at hw 80
    if (tid < 4*XS_ROW){
        *(uint4*)(Xs + xsw(tid, 10)) = z4;
        *(uint4*)(Xs + xsw(tid, 11)) = z4;
        Xs[xsw(tid, 10)] = 0x3F80;                   // bf16 1.0 (chunk10 byte0)
    }
    // P2: halo cols px0 & px65, chunks 0..11: 8 positions x 12 = 96
    if (tid < 96){
        int pp = tid/12, ch = tid - pp*12;
        int row = pp >> 1, px = (pp & 1) ? 65 : 0;
        *(uint4*)(Xs + xsw(row*XS_ROW + px, ch)) = z4;
    }
    // P3: OOB edge rows (y0==0 -> row0, y0==62 -> row3): px1..64, chunks 0..11
    if (y0 == 0 || y0 == H_-2){
        int row = (y0 == 0) ? 0 : 3;
        for (int i = tid; i < 768; i += 512){
            int px = 1 + i/12, ch = i - (i/12)*12;
            *(uint4*)(Xs + xsw(row*XS_ROW + px, ch)) = z4;
        }
    }
    // P4: t==0: h region zero, rows 0..3, px1..64, chunks 2..9 (4/thread)
    if (t == 0){
        #pragma unroll
        for (int k = 0; k < 4; ++k){
            int i = tid + (k << 9);
            int row = i >> 9; int rem = i & 511;
            int px = 1 + (rem >> 3), ch8 = rem & 7;
            *(uint4*)(Xs + xsw(row*XS_ROW + px, 2 + ch8)) = z4;
        }
    }

    // ---- stage x: 4 rows x 64 px x 2 chunks = 512 uint4 (exactly 1/thread)
    {
        int row = tid >> 7, rem = tid & 127;
        int px = rem >> 1, ch8 = rem & 1;
        int yy = y0 + row - 1;
        if (yy >= 0 && yy < H_){
            uint4 v = *(const uint4*)(xbf + ((((size_t)(b*T_ + t)*H_ + yy)*W_ + px)*16 + ch8*8));
            *(uint4*)(Xs + xsw(row*XS_ROW + px + 1, ch8)) = v;
        }
    }
    // ---- stage h: 4 rows x 64 px x 8 chunks = 2048 uint4 (4/thread)
    if (t > 0){
        #pragma unroll
        for (int k = 0; k < 4; ++k){
            int i = tid + (k << 9);
            int row = i >> 9, rem = i & 511;
            int px = rem >> 3, ch8 = rem & 7;
            int yy = y0 + row - 1;
            if (yy >= 0 && yy < H_){
                uint4 v = *(const uint4*)(hin + ((((size_t)b*H_ + yy)*W_ + px)*HID_ + ch8*8));
                *(uint4*)(Xs + xsw(row*XS_ROW + px + 1, 2 + ch8)) = v;
            }
        }
    }
    __syncthreads();

    // ---- K-loop: 27 tc = tap*3+cc iters, FULLY unrolled, tap-major (linear
    // in Wfrag). A prefetch 2-ahead, B 3-ahead, c-frag loads at tc==22.
    // A granule = (cc*4+q) ^ (pos&7): conflict-free (8 lanes/bank-cluster).
    f32x4 acc[4][4];
    #pragma unroll
    for (int g = 0; g < 4; ++g){
        #pragma unroll
        for (int mf = 0; mf < 4; ++mf) acc[g][mf] = (f32x4)0.0f;
    }

    const int posA = wm*XS_ROW + l15;                // + (ky*66+kx) const per tc
    const unsigned short* Bbase = Wfrag + (size_t)wn*512 + lane*8;
    float* cfr = cbuf + ((size_t)id << 13) + ((size_t)tid << 4);  // [blk][tid][16]

    short8 a[3][4], bb[4][3], bO[3];
    f32x4 cp[4];
    #pragma unroll
    for (int p = 0; p < 2; ++p){                     // preload A: tc=0,1
        const int tap = p/3, cc = p%3;
        const int pos = posA + (tap/3)*XS_ROW + (tap%3);
        const int ad = xsw(pos, cc*4 + q);
        #pragma unroll
        for (int mf = 0; mf < 4; ++mf)
            a[p][mf] = *(const short8*)(Xs + ad + mf*16*XS_CH);
    }
    #pragma unroll
    for (int p = 0; p < 3; ++p){                     // preload B: tc=0,1,2
        #pragma unroll
        for (int g = 0; g < 3; ++g)
            bb[p][g] = *(const short8*)(Bbase + p*8192 + g*2048);
    }

    #pragma unroll
    for (int tc = 0; tc < 27; ++tc){
        const int tap = tc/3;
        const int ca = tc % 3;                       // A slot
        const int cb = tc % 4;                       // B slot
        if (tc + 2 < 27){                            // A prefetch, distance 2
            const int ntc = tc + 2;
            const int ntap = ntc/3, ncc = ntc%3;
            const int pos = posA + (ntap/3)*XS_ROW + (ntap%3);
            const int ad = xsw(pos, ncc*4 + q);
            #pragma unroll
            for (int mf = 0; mf < 4; ++mf)
                a[ntc%3][mf] = *(const short8*)(Xs + ad + mf*16*XS_CH);
        }
        if (tc + 3 < 27){                            // B prefetch, distance 3
            const int ntc = tc + 3;
            #pragma unroll
            for (int g = 0; g < 3; ++g)
                bb[ntc%4][g] = *(const short8*)(Bbase + ntc*8192 + g*2048);
        }
        if (tc >= 9 && tc <= 11)                     // o-gate frags for tc=12..14
            bO[tc-9] = *(const short8*)(Bbase + (tc+3)*8192 + 6144);
        if (tc == 22 && t > 0){                      // c-fragment prefetch
            #pragma unroll
            for (int mf = 0; mf < 4; ++mf)
                cp[mf] = *(const f32x4*)(cfr + mf*4);
        }
        if (tap == 4){  // o-gate: center tap only (ng=12+wn; covers bias ch)
            #pragma unroll
            for (int mf = 0; mf < 4; ++mf)
                acc[3][mf] = __builtin_amdgcn_mfma_f32_16x16x32_bf16(a[ca][mf], bO[tc-12], acc[3][mf], 0,0,0);
        }
        #pragma unroll
        for (int g = 0; g < 3; ++g){
            #pragma unroll
            for (int mf = 0; mf < 4; ++mf)
                acc[g][mf] = __builtin_amdgcn_mfma_f32_16x16x32_bf16(a[ca][mf], bb[cb][g], acc[g][mf], 0,0,0);
        }
    }

    // ---- epilogue: wave-local gates; c in fragment layout, h channel-last
    const int o = wn*16 + l15;
    const int y = y0 + wm;
    #pragma unroll
    for (int mf = 0; mf < 4; ++mf){
        f32x4 cnv;
        #pragma unroll
        for (int r = 0; r < 4; ++r){
            const int px = mf*16 + q*4 + r;
            const float fv = sigm_(acc[0][mf][r]);
            const float iv = sigm_(acc[1][mf][r]);
            const float gv = tanh_(acc[2][mf][r]);
            const float ov = sigm_(acc[3][mf][r]);
            const float cprev = t ? cp[mf][r] : 0.0f;
            const float cn = cprev*fv + iv*gv;
            const float hn = tanh_(cn)*ov;
            cnv[r] = cn;
            if (t < T_-1){
                hout[(((size_t)(b*H_ + y)*W_ + px)*HID_ + o)] = f2bf(hn);
            } else {
                const size_t oidx = ((((size_t)(b*HID_ + o))*H_ + y)*W_ + px);
                out[oidx] = hn;
                out[CSTRIDE_ + oidx] = cn;
            }
        }
        if (t < T_-1) *(f32x4*)(cfr + mf*4) = cnv;   // 16B vector c store
    }
}

extern "C" void kernel_launch(void* const* d_in, const int* in_sizes, int n_in,
                              void* d_out, int out_size, void* d_ws, size_t ws_size,
                              hipStream_t stream){
    const float* x  = (const float*)d_in[0];
    const float* Wf = (const float*)d_in[1];
    const float* bf = (const float*)d_in[2];
    const float* Wi = (const float*)d_in[3];
    const float* bi = (const float*)d_in[4];
    const float* Wc = (const float*)d_in[5];
    const float* bc = (const float*)d_in[6];
    const float* Wo = (const float*)d_in[7];
    const float* bo = (const float*)d_in[8];

    // ws: Wfrag 442368 | xbf 16777216 | cbuf_frag 8388608 | hbfA | hbfB
    unsigned short* Wfrag = (unsigned short*)d_ws;
    unsigned short* xbf   = (unsigned short*)((char*)d_ws + 442368);
    float*          cbuf  = (float*)((char*)d_ws + 442368 + 16777216);
    unsigned short* hbfA  = (unsigned short*)((char*)d_ws + 442368 + 16777216 + 8388608);
    unsigned short* hbfB  = hbfA + CSTRIDE_;

    prep_all<<<dim3(2912), dim3(256), 0, stream>>>(
        x, Wf, Wi, Wc, Wo, bf, bi, bc, bo, Wfrag, xbf);

    for (int t = 0; t < T_; ++t){
        const unsigned short* hi = (t & 1) ? hbfA : hbfB;   // t==0 never reads
        unsigned short*       ho = (t & 1) ? hbfB : hbfA;
        lstm_step<<<dim3(256), dim3(512), 0, stream>>>(
            xbf, Wfrag, cbuf, hi, ho, (float*)d_out, t);
    }
}